// Round 6
// baseline (1087.200 us; speedup 1.0000x reference)
//
#include <hip/hip_runtime.h>
#include <hip/hip_bf16.h>
#include <math.h>

#define HIDDEN 100

typedef __attribute__((ext_vector_type(8))) short bf16x8;
typedef __attribute__((ext_vector_type(4))) float f32x4;

__device__ inline unsigned short f2bf(float v) {
    union { float f; unsigned u; } x; x.f = v;
    unsigned r = x.u + 0x7fff + ((x.u >> 16) & 1);   // RNE
    return (unsigned short)(r >> 16);
}

constexpr int NPTS  = 25000;
constexpr int KPAIR = 8000;
constexpr int NC    = 32;
constexpr int CHUNK = 784;    // multiple of 16; 32*784 = 25088 >= 25000
constexpr int HS    = 136;    // LDS H-slab stride (shorts)
constexpr int NB_SUP = 2000;  // sup partial blocks
constexpr int GM     = (NPTS + 31) / 32;   // 782 mlp blocks per dir
constexpr int NB_MLP = 2 * GM;
constexpr int PREP_B = (2 * NPTS * 64) / 256;  // 12500 prep blocks

// ---------------------------------------------------------------------------
// prep (+embedded w_prep): blocks < PREP_B: per row (wave) squared norm -> tn
// and bf16x128 padded row, col127 = |row|^2. Tail blocks: weight panels ->
// fragment-ordered bf16, zero-padded (4 x 64-lane units per block).
// ---------------------------------------------------------------------------
__global__ __launch_bounds__(256) void prep_kernel(
    const float* __restrict__ YW, float* __restrict__ tny, unsigned short* __restrict__ ybf,
    const float* __restrict__ XW, float* __restrict__ tnx, unsigned short* __restrict__ xbf,
    const float* __restrict__ W1, unsigned short* __restrict__ P1,
    const float* __restrict__ W2, unsigned short* __restrict__ P2,
    const float* __restrict__ W3, unsigned short* __restrict__ P3,
    const float* __restrict__ W4, unsigned short* __restrict__ P4,
    int N)
{
    const int ln = threadIdx.x & 63;
    if (blockIdx.x < PREP_B) {
        const int gw = blockIdx.x * 4 + (threadIdx.x >> 6);
        if (gw >= 2 * N) return;
        const int isY = (gw < N);
        const int r = isY ? gw : gw - N;
        const int D = isY ? 120 : 100;
        const float* src = (isY ? YW : XW) + (size_t)r * D;
        unsigned short* dst = (isY ? ybf : xbf) + (size_t)r * 128;

        const float v0 = (ln < D) ? src[ln] : 0.f;
        const float v1 = (ln + 64 < D) ? src[ln + 64] : 0.f;
        float s = fmaf(v0, v0, v1 * v1);
        #pragma unroll
        for (int o = 1; o < 64; o <<= 1) s += __shfl_xor(s, o);
        if (ln == 0) (isY ? tny : tnx)[r] = s;

        dst[ln] = f2bf(v0);
        dst[ln + 64] = (ln == 63) ? f2bf(s) : f2bf(v1);
        return;
    }
    // ---- weight panel prep ----
    int b = (blockIdx.x - PREP_B) * 4 + (threadIdx.x >> 6);
    if (b >= 116) return;
    const float* W; unsigned short* P; int DK, DN, NT;
    if (b < 28)      {          W = W1; P = P1; DK = 100; DN = 100; NT = 7; }
    else if (b < 60) { b -= 28; W = W2; P = P2; DK = 100; DN = 120; NT = 8; }
    else if (b < 88) { b -= 60; W = W3; P = P3; DK = 120; DN = 100; NT = 7; }
    else             { b -= 88; W = W4; P = P4; DK = 100; DN = 100; NT = 7; }
    const int kt = b / NT, nt = b - kt * NT;
    const int n  = nt * 16 + (ln & 15);
    const int k0 = kt * 32 + (ln >> 4) * 8;
    unsigned short* dst = P + ((size_t)(kt * NT + nt) * 64 + ln) * 8;
    #pragma unroll
    for (int j = 0; j < 8; j++) {
        const int k = k0 + j;
        const float f = (k < DK && n < DN) ? W[k * DN + n] : 0.f;
        dst[j] = f2bf(f);
    }
}

// ---------------------------------------------------------------------------
// MFMA stage helpers (layouts HW-verified: absmax 0.0 R2-R5).
// ---------------------------------------------------------------------------
template<int NT>
__device__ inline void run_stage(const bf16x8 af[4], const unsigned short* __restrict__ WP,
                                 int ln, f32x4 acc[NT])
{
    #pragma unroll
    for (int nt = 0; nt < NT; nt++) acc[nt] = (f32x4){0.f, 0.f, 0.f, 0.f};
    #pragma unroll
    for (int kt = 0; kt < 4; kt++) {
        #pragma unroll
        for (int nt = 0; nt < NT; nt++) {
            const bf16x8 wf = *reinterpret_cast<const bf16x8*>(WP + ((size_t)(kt * NT + nt) * 64 + ln) * 8);
            acc[nt] = __builtin_amdgcn_mfma_f32_16x16x32_bf16(af[kt], wf, acc[nt], 0, 0, 0);
        }
    }
}

template<int NT, int DN, bool RELU>
__device__ inline void pack_h(const f32x4 acc[NT], const float* __restrict__ B,
                              unsigned short* __restrict__ Hs, int col, int quad)
{
    #pragma unroll
    for (int nt = 0; nt < NT; nt++) {
        const int n = nt * 16 + col;
        const float b = (n < DN) ? B[n] : 0.f;
        #pragma unroll
        for (int r = 0; r < 4; r++) {
            float v = acc[nt][r] + b;
            if (RELU) v = fmaxf(v, 0.f);
            Hs[(quad * 4 + r) * HS + n] = f2bf(v);
        }
    }
}

template<int NT, int DN>
__device__ inline void store_pack(const f32x4 acc[NT], const float* __restrict__ B,
                                  float* __restrict__ Y, unsigned short* __restrict__ Hs,
                                  int rowbase, int col, int quad, int N)
{
    #pragma unroll
    for (int nt = 0; nt < NT; nt++) {
        const int n = nt * 16 + col;
        const float b = (n < DN) ? B[n] : 0.f;
        #pragma unroll
        for (int r = 0; r < 4; r++) {
            const float v = acc[nt][r] + b;
            const int row = rowbase + quad * 4 + r;
            if (n < DN && row < N) Y[(size_t)row * DN + n] = v;
            Hs[(quad * 4 + r) * HS + n] = f2bf(v);
        }
    }
}

__device__ inline void load_haf(const unsigned short* __restrict__ Hs, int col, int quad,
                                bf16x8 af[4])
{
    const unsigned short* p = Hs + col * HS + quad * 8;
    #pragma unroll
    for (int kt = 0; kt < 4; kt++)
        af[kt] = *reinterpret_cast<const bf16x8*>(p + kt * 32);
}

template<int NT, int DN>
__device__ inline float norm_stage(const f32x4 acc[NT], const float* __restrict__ B,
                                   const float* __restrict__ REF,
                                   int rowbase, int col, int quad, int N)
{
    float ra[4] = {0.f, 0.f, 0.f, 0.f};
    #pragma unroll
    for (int nt = 0; nt < NT; nt++) {
        const int n = nt * 16 + col;
        if (n < DN) {
            const float b = B[n];
            #pragma unroll
            for (int r = 0; r < 4; r++) {
                const int row = rowbase + quad * 4 + r;
                if (row < N) {
                    const float d = acc[nt][r] + b - REF[(size_t)row * DN + n];
                    ra[r] = fmaf(d, d, ra[r]);
                }
            }
        }
    }
    #pragma unroll
    for (int o = 1; o < 16; o <<= 1) {
        #pragma unroll
        for (int r = 0; r < 4; r++) ra[r] += __shfl_xor(ra[r], o);
    }
    float s = 0.f;
    if (col == 0) {
        #pragma unroll
        for (int r = 0; r < 4; r++)
            if (rowbase + quad * 4 + r < N) s += sqrtf(ra[r]);
    }
    return s;
}

// ---------------------------------------------------------------------------
// Fused 4-stage MLP chain. 128-thread blocks (2 waves x 16 rows) -> 782
// blocks/dir = ~3/CU for better distribution than R5's 391 at 1.5/CU.
// ---------------------------------------------------------------------------
template<int DIN, int DMID, int NT2, int NTF>
__global__ __launch_bounds__(128) void mlp_fused(
    const unsigned short* __restrict__ Xbf,
    const float* __restrict__ XREF,
    const unsigned short* __restrict__ WP1, const float* __restrict__ B1,
    const unsigned short* __restrict__ WP2, const float* __restrict__ B2,
    const unsigned short* __restrict__ WP3, const float* __restrict__ B3,
    const unsigned short* __restrict__ WP4, const float* __restrict__ B4,
    float* __restrict__ Y,
    float* __restrict__ part, int N)
{
    __shared__ unsigned short H[2][16 * HS];
    __shared__ float bred[8];

    const int tid = threadIdx.x;
    const int wv = tid >> 6, ln = tid & 63;
    const int col = ln & 15, quad = ln >> 4;
    const int rowbase = blockIdx.x * 32 + wv * 16;

    {
        unsigned* Hz = reinterpret_cast<unsigned*>(H[wv]);
        for (int i = ln; i < 16 * HS / 2; i += 64) Hz[i] = 0u;
    }

    bf16x8 af[4];
    {
        const int r = min(rowbase + col, N - 1);
        const unsigned short* ap = Xbf + (size_t)r * 128 + quad * 8;
        #pragma unroll
        for (int kt = 0; kt < 4; kt++) af[kt] = *reinterpret_cast<const bf16x8*>(ap + kt * 32);
    }

    f32x4 accA[7];
    run_stage<7>(af, WP1, ln, accA);
    pack_h<7, HIDDEN, true>(accA, B1, H[wv], col, quad);
    load_haf(H[wv], col, quad, af);

    f32x4 accB[NT2];
    run_stage<NT2>(af, WP2, ln, accB);
    store_pack<NT2, DMID>(accB, B2, Y, H[wv], rowbase, col, quad, N);
    load_haf(H[wv], col, quad, af);

    run_stage<7>(af, WP3, ln, accA);
    pack_h<7, HIDDEN, true>(accA, B3, H[wv], col, quad);
    load_haf(H[wv], col, quad, af);

    f32x4 accC[NTF];
    run_stage<NTF>(af, WP4, ln, accC);
    const float s = norm_stage<NTF, DIN>(accC, B4, XREF, rowbase, col, quad, N);

    if (col == 0) bred[wv * 4 + quad] = s;
    __syncthreads();
    if (tid == 0) {
        float t = 0.f;
        #pragma unroll
        for (int i = 0; i < 8; i++) t += bred[i];
        part[blockIdx.x] = t;
    }
}

// ---------------------------------------------------------------------------
// sup: wave per pair; block partial -> ws.
// ---------------------------------------------------------------------------
__global__ __launch_bounds__(256) void sup_kernel(
    const float* __restrict__ xm, const float* __restrict__ ym,
    const float* __restrict__ xw, const float* __restrict__ yw,
    const int* __restrict__ im, int K, float* __restrict__ part)
{
    const int gw = (int)((blockIdx.x * 256 + threadIdx.x) >> 6);
    const int ln = threadIdx.x & 63;
    const int wv = threadIdx.x >> 6;
    float cnt = 0.f;
    if (gw < K) {
        const int xi = im[2 * gw], yi = im[2 * gw + 1];
        const float* a = xm + (size_t)xi * 120;
        const float* b = yw + (size_t)yi * 120;
        float s1 = 0.f;
        for (int d = ln; d < 120; d += 64) { const float df = a[d] - b[d]; s1 = fmaf(df, df, s1); }
        const float* c = ym + (size_t)yi * 100;
        const float* e = xw + (size_t)xi * 100;
        float s2 = 0.f;
        for (int d = ln; d < 100; d += 64) { const float df = c[d] - e[d]; s2 = fmaf(df, df, s2); }
        #pragma unroll
        for (int o = 32; o > 0; o >>= 1) { s1 += __shfl_down(s1, o); s2 += __shfl_down(s2, o); }
        if (ln == 0) cnt = sqrtf(s1) + sqrtf(s2);
    }
    __shared__ float wsum[4];
    if (ln == 0) wsum[wv] = cnt;
    __syncthreads();
    if (threadIdx.x == 0)
        part[blockIdx.x] = wsum[0] + wsum[1] + wsum[2] + wsum[3];
}

// ---------------------------------------------------------------------------
// Gather both query panels (scaled -2, col127=1) in one launch.
// ---------------------------------------------------------------------------
__global__ __launch_bounds__(256) void gather2(
    const float* __restrict__ xm, const float* __restrict__ ym,
    const int* __restrict__ gidx,
    unsigned short* __restrict__ axf, unsigned short* __restrict__ ayf, int K)
{
    const int t = blockIdx.x * 256 + threadIdx.x;
    if (t >= 2 * K * 128) return;
    const int dir = (t >= K * 128);
    const int tt = dir ? t - K * 128 : t;
    const int r = tt >> 7, c = tt & 127;
    const float* src = dir ? ym : xm;
    const int D = dir ? 100 : 120;
    float v = 0.f;
    if (c < D) v = -2.f * src[(size_t)gidx[r * 2 + dir] * D + c];
    else if (c == 127) v = 1.f;
    (dir ? ayf : axf)[tt] = f2bf(v);
}

// ---------------------------------------------------------------------------
// MFMA 1-NN, both directions via blockIdx.z. LDS: rm UNIONED onto bsm (both
// 17408 B, disjoint in time) -> 17.7 KB -> ~8 blocks/CU resident by LDS;
// __launch_bounds__(256,6) caps VGPR for 6 waves/SIMD.
// ---------------------------------------------------------------------------
__global__ __launch_bounds__(256, 6) void nn_mfma(
    const unsigned short* __restrict__ A0, const unsigned short* __restrict__ T0,
    float* __restrict__ pm0, int* __restrict__ pi0,
    const unsigned short* __restrict__ A1, const unsigned short* __restrict__ T1,
    float* __restrict__ pm1, int* __restrict__ pi1,
    int Ntgt, int K)
{
    constexpr int BS = 136;
    __shared__ unsigned short bsm[2][32 * BS];          // 17408 B
    float (*rm)[64][17] = reinterpret_cast<float(*)[64][17]>(&bsm[0][0]);  // alias, used after final sync

    const unsigned short* A = blockIdx.z ? A1 : A0;
    const unsigned short* T = blockIdx.z ? T1 : T0;
    float* pmin = blockIdx.z ? pm1 : pm0;
    int*   pidx = blockIdx.z ? pi1 : pi0;

    const int tid = threadIdx.x;
    const int wv = tid >> 6, ln = tid & 63;
    const int col = ln & 15, quad = ln >> 4;
    const int k0 = blockIdx.x * 256;
    const int jstart = blockIdx.y * CHUNK;
    const int jend = min(jstart + CHUNK, Ntgt);
    const int nt = (jend - jstart + 31) >> 5;

    bf16x8 afrag[4][4];
    #pragma unroll
    for (int t = 0; t < 4; t++) {
        const int ar = min(k0 + wv * 64 + t * 16 + col, K - 1);
        const unsigned short* ab = A + (size_t)ar * 128 + quad * 8;
        #pragma unroll
        for (int s = 0; s < 4; s++)
            afrag[t][s] = *reinterpret_cast<const bf16x8*>(ab + s * 32);
    }

    float m[4][4];
    #pragma unroll
    for (int t = 0; t < 4; t++)
        #pragma unroll
        for (int r = 0; r < 4; r++) m[t][r] = __builtin_inff();

    const unsigned bigw = ((unsigned)f2bf(1e30f)) << 16;

    {
        #pragma unroll
        for (int half = 0; half < 2; half++) {
            const int c = tid + half * 256;
            const int r = c >> 4, off = c & 15;
            const int j = jstart + r;
            uint4 v;
            if (j < jend) v = reinterpret_cast<const uint4*>(T + (size_t)j * 128)[off];
            else { v.x = 0; v.y = 0; v.z = 0; v.w = (off == 15) ? bigw : 0u; }
            *reinterpret_cast<uint4*>(&bsm[0][r * BS + off * 8]) = v;
        }
    }
    __syncthreads();

    for (int ti = 0; ti < nt; ti++) {
        const int cur = ti & 1;
        const bool have = (ti + 1 < nt);
        uint4 v0, v1;
        if (have) {
            #pragma unroll
            for (int half = 0; half < 2; half++) {
                const int c = tid + half * 256;
                const int r = c >> 4, off = c & 15;
                const int j = jstart + (ti + 1) * 32 + r;
                uint4 v;
                if (j < jend) v = reinterpret_cast<const uint4*>(T + (size_t)j * 128)[off];
                else { v.x = 0; v.y = 0; v.z = 0; v.w = (off == 15) ? bigw : 0u; }
                if (half == 0) v0 = v; else v1 = v;
            }
        }

        const unsigned short* buf = bsm[cur];
        const unsigned lowbase = (unsigned)((jstart + ti * 32) >> 4);
        #pragma unroll
        for (int sub = 0; sub < 2; sub++) {
            bf16x8 bfr[4];
            const unsigned short* bb = buf + (sub * 16 + col) * BS + quad * 8;
            #pragma unroll
            for (int s = 0; s < 4; s++)
                bfr[s] = *reinterpret_cast<const bf16x8*>(bb + s * 32);
            const unsigned low = lowbase + sub;
            #pragma unroll
            for (int t = 0; t < 4; t++) {
                f32x4 acc = {0.f, 0.f, 0.f, 0.f};
                #pragma unroll
                for (int s = 0; s < 4; s++)
                    acc = __builtin_amdgcn_mfma_f32_16x16x32_bf16(afrag[t][s], bfr[s], acc, 0, 0, 0);
                #pragma unroll
                for (int r = 0; r < 4; r++) {
                    const unsigned u = (__float_as_uint(acc[r]) & 0xFFFFF800u) | low;
                    m[t][r] = fminf(m[t][r], __uint_as_float(u));
                }
            }
        }

        if (have) {
            {
                const int c = tid, r = c >> 4, off = c & 15;
                *reinterpret_cast<uint4*>(&bsm[cur ^ 1][r * BS + off * 8]) = v0;
            }
            {
                const int c = tid + 256, r = c >> 4, off = c & 15;
                *reinterpret_cast<uint4*>(&bsm[cur ^ 1][r * BS + off * 8]) = v1;
            }
        }
        __syncthreads();
    }

    // ---- reduction (rm aliases bsm; all reads of bsm completed) ----
    #pragma unroll
    for (int t = 0; t < 4; t++)
        #pragma unroll
        for (int r = 0; r < 4; r++)
            rm[wv][t * 16 + quad * 4 + r][col] = m[t][r];
    __syncthreads();

    const int k = k0 + tid;
    if (k < K) {
        const int w = tid >> 6, rr = tid & 63;
        float best = rm[w][rr][0];
        int bc = 0;
        #pragma unroll
        for (int c = 1; c < 16; c++) {
            const float v = rm[w][rr][c];
            if (v < best) { best = v; bc = c; }
        }
        const int j = (int)(((__float_as_uint(best) & 0x7FFu) << 4) | (unsigned)bc);
        pmin[(size_t)k * NC + blockIdx.y] = best;
        pidx[(size_t)k * NC + blockIdx.y] = j;
    }
}

// ---------------------------------------------------------------------------
// finish_all: mismatch indicators + sup partials + mlp partials. 64 atomics.
// ---------------------------------------------------------------------------
__global__ __launch_bounds__(256) void finish_all(
    const int* __restrict__ im,
    const float* __restrict__ pm0, const int* __restrict__ pi0,
    const float* __restrict__ pm1, const int* __restrict__ pi1,
    const float* __restrict__ part_sup, const float* __restrict__ part_mlp,
    int K, float* __restrict__ out, float inv_k, float inv_n)
{
    const int gid = blockIdx.x * 256 + threadIdx.x;
    const int stride = gridDim.x * 256;
    float local = 0.f;

    for (int p = gid; p < 2 * K; p += stride) {
        const int dir = (p >= K);
        const int kk = dir ? p - K : p;
        const float* pm = dir ? pm1 : pm0;
        const int*   pi = dir ? pi1 : pi0;
        float best = __builtin_inff();
        int bi = 0x7fffffff;
        #pragma unroll
        for (int c = 0; c < NC; c++) {
            const float v = pm[(size_t)kk * NC + c];
            const int  ii = pi[(size_t)kk * NC + c];
            if (v < best || (v == best && ii < bi)) { best = v; bi = ii; }
        }
        if (bi != im[2 * kk + dir]) local += inv_k;
    }
    for (int i = gid; i < NB_SUP; i += stride) local += part_sup[i] * inv_k;
    for (int i = gid; i < NB_MLP; i += stride) local += part_mlp[i] * inv_n;

    #pragma unroll
    for (int o = 32; o > 0; o >>= 1) local += __shfl_down(local, o);
    __shared__ float wsum[4];
    if ((threadIdx.x & 63) == 0) wsum[threadIdx.x >> 6] = local;
    __syncthreads();
    if (threadIdx.x == 0) {
        const float t = wsum[0] + wsum[1] + wsum[2] + wsum[3];
        if (t != 0.f) atomicAdd(out, t);
    }
}

// ---------------------------------------------------------------------------
extern "C" void kernel_launch(void* const* d_in, const int* in_sizes, int n_in,
                              void* d_out, int out_size, void* d_ws, size_t ws_size,
                              hipStream_t stream)
{
    const float* xw    = (const float*)d_in[0];
    const float* yw    = (const float*)d_in[1];
    const float* fx_w1 = (const float*)d_in[2];
    const float* fx_b1 = (const float*)d_in[3];
    const float* fx_w2 = (const float*)d_in[4];
    const float* fx_b2 = (const float*)d_in[5];
    const float* gy_w1 = (const float*)d_in[6];
    const float* gy_b1 = (const float*)d_in[7];
    const float* gy_w2 = (const float*)d_in[8];
    const float* gy_b2 = (const float*)d_in[9];
    const int*   imap  = (const int*)d_in[10];
    float* out = (float*)d_out;
    float* ws  = (float*)d_ws;

    constexpr int N = NPTS, K = KPAIR;

    float* xm      = ws;                           // N*120
    float* ym      = xm + (size_t)N * 120;         // N*100
    float* tn_y    = ym + (size_t)N * 100;         // N
    float* tn_x    = tn_y + N;                     // N
    float* pmin_fx = tn_x + N;                     // K*NC
    int*   pidx_fx = (int*)(pmin_fx + (size_t)K * NC);
    float* pmin_gy = (float*)(pidx_fx + (size_t)K * NC);
    int*   pidx_gy = (int*)(pmin_gy + (size_t)K * NC);
    unsigned short* ybf = (unsigned short*)(pidx_gy + (size_t)K * NC); // N*128
    unsigned short* xbf = ybf + (size_t)N * 128;
    unsigned short* axf = xbf + (size_t)N * 128;   // K*128
    unsigned short* ayf = axf + (size_t)K * 128;
    unsigned short* wp_fx1 = ayf + (size_t)K * 128;  // 28*512
    unsigned short* wp_fx2 = wp_fx1 + 28 * 512;      // 32*512
    unsigned short* wp_gy1 = wp_fx2 + 32 * 512;      // 28*512
    unsigned short* wp_gy2 = wp_gy1 + 28 * 512;      // 28*512
    float* part_sup = (float*)(wp_gy2 + 28 * 512);   // NB_SUP
    float* part_mlp = part_sup + NB_SUP;             // NB_MLP

    hipMemsetAsync(d_out, 0, sizeof(float), stream);

    prep_kernel<<<PREP_B + 29, 256, 0, stream>>>(
        yw, tn_y, ybf, xw, tn_x, xbf,
        fx_w1, wp_fx1, fx_w2, wp_fx2, gy_w1, wp_gy1, gy_w2, wp_gy2, N);

    mlp_fused<100, 120, 8, 7><<<GM, 128, 0, stream>>>(
        xbf, xw, wp_fx1, fx_b1, wp_fx2, fx_b2, wp_gy1, gy_b1, wp_gy2, gy_b2,
        xm, part_mlp, N);
    mlp_fused<120, 100, 7, 8><<<GM, 128, 0, stream>>>(
        ybf, yw, wp_gy1, gy_b1, wp_gy2, gy_b2, wp_fx1, fx_b1, wp_fx2, fx_b2,
        ym, part_mlp + GM, N);

    sup_kernel<<<NB_SUP, 256, 0, stream>>>(xm, ym, xw, yw, imap, K, part_sup);

    gather2<<<(2 * K * 128) / 256, 256, 0, stream>>>(xm, ym, imap, axf, ayf, K);

    dim3 g1((K + 255) / 256, NC, 2);
    nn_mfma<<<g1, 256, 0, stream>>>(axf, ybf, pmin_fx, pidx_fx,
                                    ayf, xbf, pmin_gy, pidx_gy, N, K);

    finish_all<<<64, 256, 0, stream>>>(
        imap, pmin_fx, pidx_fx, pmin_gy, pidx_gy, part_sup, part_mlp,
        K, out, 1.f / K, 1.f / N);
}

// Round 7
// 723.297 us; speedup vs baseline: 1.5031x; 1.5031x over previous
//
#include <hip/hip_runtime.h>
#include <hip/hip_bf16.h>
#include <math.h>

#define HIDDEN 100

typedef __attribute__((ext_vector_type(8))) short bf16x8;
typedef __attribute__((ext_vector_type(4))) float f32x4;

__device__ inline unsigned short f2bf(float v) {
    union { float f; unsigned u; } x; x.f = v;
    unsigned r = x.u + 0x7fff + ((x.u >> 16) & 1);   // RNE
    return (unsigned short)(r >> 16);
}

constexpr int NPTS  = 25000;
constexpr int KPAIR = 8000;
constexpr int NC    = 32;
constexpr int CHUNK = 784;    // multiple of 16; 32*784 = 25088 >= 25000
constexpr int HS    = 136;    // LDS H-slab stride (shorts)
constexpr int NB_SUP = 2000;  // sup partial blocks
constexpr int GM     = (NPTS + 31) / 32;   // 782 mlp blocks per dir
constexpr int NB_MLP = 2 * GM;
constexpr int PREP_B = (2 * NPTS * 64) / 256;  // 12500 prep blocks

// ---------------------------------------------------------------------------
// prep (+embedded w_prep): blocks < PREP_B: per row (wave) squared norm -> tn
// and bf16x128 padded row, col127 = |row|^2. Tail blocks: weight panels ->
// fragment-ordered bf16, zero-padded (4 x 64-lane units per block).
// ---------------------------------------------------------------------------
__global__ __launch_bounds__(256) void prep_kernel(
    const float* __restrict__ YW, float* __restrict__ tny, unsigned short* __restrict__ ybf,
    const float* __restrict__ XW, float* __restrict__ tnx, unsigned short* __restrict__ xbf,
    const float* __restrict__ W1, unsigned short* __restrict__ P1,
    const float* __restrict__ W2, unsigned short* __restrict__ P2,
    const float* __restrict__ W3, unsigned short* __restrict__ P3,
    const float* __restrict__ W4, unsigned short* __restrict__ P4,
    int N)
{
    const int ln = threadIdx.x & 63;
    if (blockIdx.x < PREP_B) {
        const int gw = blockIdx.x * 4 + (threadIdx.x >> 6);
        if (gw >= 2 * N) return;
        const int isY = (gw < N);
        const int r = isY ? gw : gw - N;
        const int D = isY ? 120 : 100;
        const float* src = (isY ? YW : XW) + (size_t)r * D;
        unsigned short* dst = (isY ? ybf : xbf) + (size_t)r * 128;

        const float v0 = (ln < D) ? src[ln] : 0.f;
        const float v1 = (ln + 64 < D) ? src[ln + 64] : 0.f;
        float s = fmaf(v0, v0, v1 * v1);
        #pragma unroll
        for (int o = 1; o < 64; o <<= 1) s += __shfl_xor(s, o);
        if (ln == 0) (isY ? tny : tnx)[r] = s;

        dst[ln] = f2bf(v0);
        dst[ln + 64] = (ln == 63) ? f2bf(s) : f2bf(v1);
        return;
    }
    // ---- weight panel prep ----
    int b = (blockIdx.x - PREP_B) * 4 + (threadIdx.x >> 6);
    if (b >= 116) return;
    const float* W; unsigned short* P; int DK, DN, NT;
    if (b < 28)      {          W = W1; P = P1; DK = 100; DN = 100; NT = 7; }
    else if (b < 60) { b -= 28; W = W2; P = P2; DK = 100; DN = 120; NT = 8; }
    else if (b < 88) { b -= 60; W = W3; P = P3; DK = 120; DN = 100; NT = 7; }
    else             { b -= 88; W = W4; P = P4; DK = 100; DN = 100; NT = 7; }
    const int kt = b / NT, nt = b - kt * NT;
    const int n  = nt * 16 + (ln & 15);
    const int k0 = kt * 32 + (ln >> 4) * 8;
    unsigned short* dst = P + ((size_t)(kt * NT + nt) * 64 + ln) * 8;
    #pragma unroll
    for (int j = 0; j < 8; j++) {
        const int k = k0 + j;
        const float f = (k < DK && n < DN) ? W[k * DN + n] : 0.f;
        dst[j] = f2bf(f);
    }
}

// ---------------------------------------------------------------------------
// MFMA stage helpers (layouts HW-verified: absmax 0.0 R2-R6).
// ---------------------------------------------------------------------------
template<int NT>
__device__ inline void run_stage(const bf16x8 af[4], const unsigned short* __restrict__ WP,
                                 int ln, f32x4 acc[NT])
{
    #pragma unroll
    for (int nt = 0; nt < NT; nt++) acc[nt] = (f32x4){0.f, 0.f, 0.f, 0.f};
    #pragma unroll
    for (int kt = 0; kt < 4; kt++) {
        #pragma unroll
        for (int nt = 0; nt < NT; nt++) {
            const bf16x8 wf = *reinterpret_cast<const bf16x8*>(WP + ((size_t)(kt * NT + nt) * 64 + ln) * 8);
            acc[nt] = __builtin_amdgcn_mfma_f32_16x16x32_bf16(af[kt], wf, acc[nt], 0, 0, 0);
        }
    }
}

template<int NT, int DN, bool RELU>
__device__ inline void pack_h(const f32x4 acc[NT], const float* __restrict__ B,
                              unsigned short* __restrict__ Hs, int col, int quad)
{
    #pragma unroll
    for (int nt = 0; nt < NT; nt++) {
        const int n = nt * 16 + col;
        const float b = (n < DN) ? B[n] : 0.f;
        #pragma unroll
        for (int r = 0; r < 4; r++) {
            float v = acc[nt][r] + b;
            if (RELU) v = fmaxf(v, 0.f);
            Hs[(quad * 4 + r) * HS + n] = f2bf(v);
        }
    }
}

template<int NT, int DN>
__device__ inline void store_pack(const f32x4 acc[NT], const float* __restrict__ B,
                                  float* __restrict__ Y, unsigned short* __restrict__ Hs,
                                  int rowbase, int col, int quad, int N)
{
    #pragma unroll
    for (int nt = 0; nt < NT; nt++) {
        const int n = nt * 16 + col;
        const float b = (n < DN) ? B[n] : 0.f;
        #pragma unroll
        for (int r = 0; r < 4; r++) {
            const float v = acc[nt][r] + b;
            const int row = rowbase + quad * 4 + r;
            if (n < DN && row < N) Y[(size_t)row * DN + n] = v;
            Hs[(quad * 4 + r) * HS + n] = f2bf(v);
        }
    }
}

__device__ inline void load_haf(const unsigned short* __restrict__ Hs, int col, int quad,
                                bf16x8 af[4])
{
    const unsigned short* p = Hs + col * HS + quad * 8;
    #pragma unroll
    for (int kt = 0; kt < 4; kt++)
        af[kt] = *reinterpret_cast<const bf16x8*>(p + kt * 32);
}

template<int NT, int DN>
__device__ inline float norm_stage(const f32x4 acc[NT], const float* __restrict__ B,
                                   const float* __restrict__ REF,
                                   int rowbase, int col, int quad, int N)
{
    float ra[4] = {0.f, 0.f, 0.f, 0.f};
    #pragma unroll
    for (int nt = 0; nt < NT; nt++) {
        const int n = nt * 16 + col;
        if (n < DN) {
            const float b = B[n];
            #pragma unroll
            for (int r = 0; r < 4; r++) {
                const int row = rowbase + quad * 4 + r;
                if (row < N) {
                    const float d = acc[nt][r] + b - REF[(size_t)row * DN + n];
                    ra[r] = fmaf(d, d, ra[r]);
                }
            }
        }
    }
    #pragma unroll
    for (int o = 1; o < 16; o <<= 1) {
        #pragma unroll
        for (int r = 0; r < 4; r++) ra[r] += __shfl_xor(ra[r], o);
    }
    float s = 0.f;
    if (col == 0) {
        #pragma unroll
        for (int r = 0; r < 4; r++)
            if (rowbase + quad * 4 + r < N) s += sqrtf(ra[r]);
    }
    return s;
}

// ---------------------------------------------------------------------------
// Fused 4-stage MLP chain. 128-thread blocks (2 waves x 16 rows).
// ---------------------------------------------------------------------------
template<int DIN, int DMID, int NT2, int NTF>
__global__ __launch_bounds__(128) void mlp_fused(
    const unsigned short* __restrict__ Xbf,
    const float* __restrict__ XREF,
    const unsigned short* __restrict__ WP1, const float* __restrict__ B1,
    const unsigned short* __restrict__ WP2, const float* __restrict__ B2,
    const unsigned short* __restrict__ WP3, const float* __restrict__ B3,
    const unsigned short* __restrict__ WP4, const float* __restrict__ B4,
    float* __restrict__ Y,
    float* __restrict__ part, int N)
{
    __shared__ unsigned short H[2][16 * HS];
    __shared__ float bred[8];

    const int tid = threadIdx.x;
    const int wv = tid >> 6, ln = tid & 63;
    const int col = ln & 15, quad = ln >> 4;
    const int rowbase = blockIdx.x * 32 + wv * 16;

    {
        unsigned* Hz = reinterpret_cast<unsigned*>(H[wv]);
        for (int i = ln; i < 16 * HS / 2; i += 64) Hz[i] = 0u;
    }

    bf16x8 af[4];
    {
        const int r = min(rowbase + col, N - 1);
        const unsigned short* ap = Xbf + (size_t)r * 128 + quad * 8;
        #pragma unroll
        for (int kt = 0; kt < 4; kt++) af[kt] = *reinterpret_cast<const bf16x8*>(ap + kt * 32);
    }

    f32x4 accA[7];
    run_stage<7>(af, WP1, ln, accA);
    pack_h<7, HIDDEN, true>(accA, B1, H[wv], col, quad);
    load_haf(H[wv], col, quad, af);

    f32x4 accB[NT2];
    run_stage<NT2>(af, WP2, ln, accB);
    store_pack<NT2, DMID>(accB, B2, Y, H[wv], rowbase, col, quad, N);
    load_haf(H[wv], col, quad, af);

    run_stage<7>(af, WP3, ln, accA);
    pack_h<7, HIDDEN, true>(accA, B3, H[wv], col, quad);
    load_haf(H[wv], col, quad, af);

    f32x4 accC[NTF];
    run_stage<NTF>(af, WP4, ln, accC);
    const float s = norm_stage<NTF, DIN>(accC, B4, XREF, rowbase, col, quad, N);

    if (col == 0) bred[wv * 4 + quad] = s;
    __syncthreads();
    if (tid == 0) {
        float t = 0.f;
        #pragma unroll
        for (int i = 0; i < 8; i++) t += bred[i];
        part[blockIdx.x] = t;
    }
}

// ---------------------------------------------------------------------------
// sup: wave per pair; block partial -> ws.
// ---------------------------------------------------------------------------
__global__ __launch_bounds__(256) void sup_kernel(
    const float* __restrict__ xm, const float* __restrict__ ym,
    const float* __restrict__ xw, const float* __restrict__ yw,
    const int* __restrict__ im, int K, float* __restrict__ part)
{
    const int gw = (int)((blockIdx.x * 256 + threadIdx.x) >> 6);
    const int ln = threadIdx.x & 63;
    const int wv = threadIdx.x >> 6;
    float cnt = 0.f;
    if (gw < K) {
        const int xi = im[2 * gw], yi = im[2 * gw + 1];
        const float* a = xm + (size_t)xi * 120;
        const float* b = yw + (size_t)yi * 120;
        float s1 = 0.f;
        for (int d = ln; d < 120; d += 64) { const float df = a[d] - b[d]; s1 = fmaf(df, df, s1); }
        const float* c = ym + (size_t)yi * 100;
        const float* e = xw + (size_t)xi * 100;
        float s2 = 0.f;
        for (int d = ln; d < 100; d += 64) { const float df = c[d] - e[d]; s2 = fmaf(df, df, s2); }
        #pragma unroll
        for (int o = 32; o > 0; o >>= 1) { s1 += __shfl_down(s1, o); s2 += __shfl_down(s2, o); }
        if (ln == 0) cnt = sqrtf(s1) + sqrtf(s2);
    }
    __shared__ float wsum[4];
    if (ln == 0) wsum[wv] = cnt;
    __syncthreads();
    if (threadIdx.x == 0)
        part[blockIdx.x] = wsum[0] + wsum[1] + wsum[2] + wsum[3];
}

// ---------------------------------------------------------------------------
// Gather both query panels (scaled -2, col127=1) in one launch.
// ---------------------------------------------------------------------------
__global__ __launch_bounds__(256) void gather2(
    const float* __restrict__ xm, const float* __restrict__ ym,
    const int* __restrict__ gidx,
    unsigned short* __restrict__ axf, unsigned short* __restrict__ ayf, int K)
{
    const int t = blockIdx.x * 256 + threadIdx.x;
    if (t >= 2 * K * 128) return;
    const int dir = (t >= K * 128);
    const int tt = dir ? t - K * 128 : t;
    const int r = tt >> 7, c = tt & 127;
    const float* src = dir ? ym : xm;
    const int D = dir ? 100 : 120;
    float v = 0.f;
    if (c < D) v = -2.f * src[(size_t)gidx[r * 2 + dir] * D + c];
    else if (c == 127) v = 1.f;
    (dir ? ayf : axf)[tt] = f2bf(v);
}

// ---------------------------------------------------------------------------
// MFMA 1-NN, both directions via blockIdx.z. LDS: rm unioned onto bsm
// (17.4 KB -> ~8 blocks/CU). launch_bounds (256,4): VGPR cap 128 -- the
// kernel needs ~72 live (afrag 64 + addr); R6's (256,6) cap of ~85 forced
// a scratch-spill storm (FETCH 2.7 GB, 4.4 TB/s HBM). Never cap below live.
// ---------------------------------------------------------------------------
__global__ __launch_bounds__(256, 4) void nn_mfma(
    const unsigned short* __restrict__ A0, const unsigned short* __restrict__ T0,
    float* __restrict__ pm0, int* __restrict__ pi0,
    const unsigned short* __restrict__ A1, const unsigned short* __restrict__ T1,
    float* __restrict__ pm1, int* __restrict__ pi1,
    int Ntgt, int K)
{
    constexpr int BS = 136;
    __shared__ unsigned short bsm[2][32 * BS];          // 17408 B
    float (*rm)[64][17] = reinterpret_cast<float(*)[64][17]>(&bsm[0][0]);  // alias, used after final sync

    const unsigned short* A = blockIdx.z ? A1 : A0;
    const unsigned short* T = blockIdx.z ? T1 : T0;
    float* pmin = blockIdx.z ? pm1 : pm0;
    int*   pidx = blockIdx.z ? pi1 : pi0;

    const int tid = threadIdx.x;
    const int wv = tid >> 6, ln = tid & 63;
    const int col = ln & 15, quad = ln >> 4;
    const int k0 = blockIdx.x * 256;
    const int jstart = blockIdx.y * CHUNK;
    const int jend = min(jstart + CHUNK, Ntgt);
    const int nt = (jend - jstart + 31) >> 5;

    bf16x8 afrag[4][4];
    #pragma unroll
    for (int t = 0; t < 4; t++) {
        const int ar = min(k0 + wv * 64 + t * 16 + col, K - 1);
        const unsigned short* ab = A + (size_t)ar * 128 + quad * 8;
        #pragma unroll
        for (int s = 0; s < 4; s++)
            afrag[t][s] = *reinterpret_cast<const bf16x8*>(ab + s * 32);
    }

    float m[4][4];
    #pragma unroll
    for (int t = 0; t < 4; t++)
        #pragma unroll
        for (int r = 0; r < 4; r++) m[t][r] = __builtin_inff();

    const unsigned bigw = ((unsigned)f2bf(1e30f)) << 16;

    {
        #pragma unroll
        for (int half = 0; half < 2; half++) {
            const int c = tid + half * 256;
            const int r = c >> 4, off = c & 15;
            const int j = jstart + r;
            uint4 v;
            if (j < jend) v = reinterpret_cast<const uint4*>(T + (size_t)j * 128)[off];
            else { v.x = 0; v.y = 0; v.z = 0; v.w = (off == 15) ? bigw : 0u; }
            *reinterpret_cast<uint4*>(&bsm[0][r * BS + off * 8]) = v;
        }
    }
    __syncthreads();

    for (int ti = 0; ti < nt; ti++) {
        const int cur = ti & 1;
        const bool have = (ti + 1 < nt);
        uint4 v0, v1;
        if (have) {
            #pragma unroll
            for (int half = 0; half < 2; half++) {
                const int c = tid + half * 256;
                const int r = c >> 4, off = c & 15;
                const int j = jstart + (ti + 1) * 32 + r;
                uint4 v;
                if (j < jend) v = reinterpret_cast<const uint4*>(T + (size_t)j * 128)[off];
                else { v.x = 0; v.y = 0; v.z = 0; v.w = (off == 15) ? bigw : 0u; }
                if (half == 0) v0 = v; else v1 = v;
            }
        }

        const unsigned short* buf = bsm[cur];
        const unsigned lowbase = (unsigned)((jstart + ti * 32) >> 4);
        #pragma unroll
        for (int sub = 0; sub < 2; sub++) {
            bf16x8 bfr[4];
            const unsigned short* bb = buf + (sub * 16 + col) * BS + quad * 8;
            #pragma unroll
            for (int s = 0; s < 4; s++)
                bfr[s] = *reinterpret_cast<const bf16x8*>(bb + s * 32);
            const unsigned low = lowbase + sub;
            #pragma unroll
            for (int t = 0; t < 4; t++) {
                f32x4 acc = {0.f, 0.f, 0.f, 0.f};
                #pragma unroll
                for (int s = 0; s < 4; s++)
                    acc = __builtin_amdgcn_mfma_f32_16x16x32_bf16(afrag[t][s], bfr[s], acc, 0, 0, 0);
                #pragma unroll
                for (int r = 0; r < 4; r++) {
                    const unsigned u = (__float_as_uint(acc[r]) & 0xFFFFF800u) | low;
                    m[t][r] = fminf(m[t][r], __uint_as_float(u));
                }
            }
        }

        if (have) {
            {
                const int c = tid, r = c >> 4, off = c & 15;
                *reinterpret_cast<uint4*>(&bsm[cur ^ 1][r * BS + off * 8]) = v0;
            }
            {
                const int c = tid + 256, r = c >> 4, off = c & 15;
                *reinterpret_cast<uint4*>(&bsm[cur ^ 1][r * BS + off * 8]) = v1;
            }
        }
        __syncthreads();
    }

    // ---- reduction (rm aliases bsm; all reads of bsm completed) ----
    #pragma unroll
    for (int t = 0; t < 4; t++)
        #pragma unroll
        for (int r = 0; r < 4; r++)
            rm[wv][t * 16 + quad * 4 + r][col] = m[t][r];
    __syncthreads();

    const int k = k0 + tid;
    if (k < K) {
        const int w = tid >> 6, rr = tid & 63;
        float best = rm[w][rr][0];
        int bc = 0;
        #pragma unroll
        for (int c = 1; c < 16; c++) {
            const float v = rm[w][rr][c];
            if (v < best) { best = v; bc = c; }
        }
        const int j = (int)(((__float_as_uint(best) & 0x7FFu) << 4) | (unsigned)bc);
        pmin[(size_t)k * NC + blockIdx.y] = best;
        pidx[(size_t)k * NC + blockIdx.y] = j;
    }
}

// ---------------------------------------------------------------------------
// finish_all: mismatch indicators + sup partials + mlp partials. 64 atomics.
// ---------------------------------------------------------------------------
__global__ __launch_bounds__(256) void finish_all(
    const int* __restrict__ im,
    const float* __restrict__ pm0, const int* __restrict__ pi0,
    const float* __restrict__ pm1, const int* __restrict__ pi1,
    const float* __restrict__ part_sup, const float* __restrict__ part_mlp,
    int K, float* __restrict__ out, float inv_k, float inv_n)
{
    const int gid = blockIdx.x * 256 + threadIdx.x;
    const int stride = gridDim.x * 256;
    float local = 0.f;

    for (int p = gid; p < 2 * K; p += stride) {
        const int dir = (p >= K);
        const int kk = dir ? p - K : p;
        const float* pm = dir ? pm1 : pm0;
        const int*   pi = dir ? pi1 : pi0;
        float best = __builtin_inff();
        int bi = 0x7fffffff;
        #pragma unroll
        for (int c = 0; c < NC; c++) {
            const float v = pm[(size_t)kk * NC + c];
            const int  ii = pi[(size_t)kk * NC + c];
            if (v < best || (v == best && ii < bi)) { best = v; bi = ii; }
        }
        if (bi != im[2 * kk + dir]) local += inv_k;
    }
    for (int i = gid; i < NB_SUP; i += stride) local += part_sup[i] * inv_k;
    for (int i = gid; i < NB_MLP; i += stride) local += part_mlp[i] * inv_n;

    #pragma unroll
    for (int o = 32; o > 0; o >>= 1) local += __shfl_down(local, o);
    __shared__ float wsum[4];
    if ((threadIdx.x & 63) == 0) wsum[threadIdx.x >> 6] = local;
    __syncthreads();
    if (threadIdx.x == 0) {
        const float t = wsum[0] + wsum[1] + wsum[2] + wsum[3];
        if (t != 0.f) atomicAdd(out, t);
    }
}

// ---------------------------------------------------------------------------
extern "C" void kernel_launch(void* const* d_in, const int* in_sizes, int n_in,
                              void* d_out, int out_size, void* d_ws, size_t ws_size,
                              hipStream_t stream)
{
    const float* xw    = (const float*)d_in[0];
    const float* yw    = (const float*)d_in[1];
    const float* fx_w1 = (const float*)d_in[2];
    const float* fx_b1 = (const float*)d_in[3];
    const float* fx_w2 = (const float*)d_in[4];
    const float* fx_b2 = (const float*)d_in[5];
    const float* gy_w1 = (const float*)d_in[6];
    const float* gy_b1 = (const float*)d_in[7];
    const float* gy_w2 = (const float*)d_in[8];
    const float* gy_b2 = (const float*)d_in[9];
    const int*   imap  = (const int*)d_in[10];
    float* out = (float*)d_out;
    float* ws  = (float*)d_ws;

    constexpr int N = NPTS, K = KPAIR;

    float* xm      = ws;                           // N*120
    float* ym      = xm + (size_t)N * 120;         // N*100
    float* tn_y    = ym + (size_t)N * 100;         // N
    float* tn_x    = tn_y + N;                     // N
    float* pmin_fx = tn_x + N;                     // K*NC
    int*   pidx_fx = (int*)(pmin_fx + (size_t)K * NC);
    float* pmin_gy = (float*)(pidx_fx + (size_t)K * NC);
    int*   pidx_gy = (int*)(pmin_gy + (size_t)K * NC);
    unsigned short* ybf = (unsigned short*)(pidx_gy + (size_t)K * NC); // N*128
    unsigned short* xbf = ybf + (size_t)N * 128;
    unsigned short* axf = xbf + (size_t)N * 128;   // K*128
    unsigned short* ayf = axf + (size_t)K * 128;
    unsigned short* wp_fx1 = ayf + (size_t)K * 128;  // 28*512
    unsigned short* wp_fx2 = wp_fx1 + 28 * 512;      // 32*512
    unsigned short* wp_gy1 = wp_fx2 + 32 * 512;      // 28*512
    unsigned short* wp_gy2 = wp_gy1 + 28 * 512;      // 28*512
    float* part_sup = (float*)(wp_gy2 + 28 * 512);   // NB_SUP
    float* part_mlp = part_sup + NB_SUP;             // NB_MLP

    hipMemsetAsync(d_out, 0, sizeof(float), stream);

    prep_kernel<<<PREP_B + 29, 256, 0, stream>>>(
        yw, tn_y, ybf, xw, tn_x, xbf,
        fx_w1, wp_fx1, fx_w2, wp_fx2, gy_w1, wp_gy1, gy_w2, wp_gy2, N);

    mlp_fused<100, 120, 8, 7><<<GM, 128, 0, stream>>>(
        xbf, xw, wp_fx1, fx_b1, wp_fx2, fx_b2, wp_gy1, gy_b1, wp_gy2, gy_b2,
        xm, part_mlp, N);
    mlp_fused<120, 100, 7, 8><<<GM, 128, 0, stream>>>(
        ybf, yw, wp_gy1, gy_b1, wp_gy2, gy_b2, wp_fx1, fx_b1, wp_fx2, fx_b2,
        ym, part_mlp + GM, N);

    sup_kernel<<<NB_SUP, 256, 0, stream>>>(xm, ym, xw, yw, imap, K, part_sup);

    gather2<<<(2 * K * 128) / 256, 256, 0, stream>>>(xm, ym, imap, axf, ayf, K);

    dim3 g1((K + 255) / 256, NC, 2);
    nn_mfma<<<g1, 256, 0, stream>>>(axf, ybf, pmin_fx, pidx_fx,
                                    ayf, xbf, pmin_gy, pidx_gy, N, K);

    finish_all<<<64, 256, 0, stream>>>(
        imap, pmin_fx, pidx_fx, pmin_gy, pidx_gy, part_sup, part_mlp,
        K, out, 1.f / K, 1.f / N);
}

// Round 8
// 246.539 us; speedup vs baseline: 4.4099x; 2.9338x over previous
//
#include <hip/hip_runtime.h>
#include <hip/hip_bf16.h>
#include <math.h>

#define HIDDEN 100

typedef __attribute__((ext_vector_type(8))) short bf16x8;
typedef __attribute__((ext_vector_type(4))) float f32x4;

__device__ inline unsigned short f2bf(float v) {
    union { float f; unsigned u; } x; x.f = v;
    unsigned r = x.u + 0x7fff + ((x.u >> 16) & 1);   // RNE
    return (unsigned short)(r >> 16);
}

constexpr int NPTS  = 25000;
constexpr int KPAIR = 8000;
constexpr int NC    = 32;
constexpr int CHUNK = 784;    // multiple of 16; 32*784 = 25088 >= 25000
constexpr int HS    = 136;    // LDS H-slab stride (shorts)
constexpr int NB_SUP = 2000;  // sup partial blocks
constexpr int GM     = (NPTS + 31) / 32;   // 782 mlp blocks per dir
constexpr int NB_MLP = 2 * GM;
constexpr int PREP_B = (2 * NPTS * 64) / 256;  // 12500 prep blocks

// ---------------------------------------------------------------------------
// prep (+embedded w_prep): blocks < PREP_B: per row (wave) squared norm -> tn
// and bf16x128 padded row, col127 = |row|^2. Tail blocks: weight panels ->
// fragment-ordered bf16, zero-padded (4 x 64-lane units per block).
// ---------------------------------------------------------------------------
__global__ __launch_bounds__(256) void prep_kernel(
    const float* __restrict__ YW, float* __restrict__ tny, unsigned short* __restrict__ ybf,
    const float* __restrict__ XW, float* __restrict__ tnx, unsigned short* __restrict__ xbf,
    const float* __restrict__ W1, unsigned short* __restrict__ P1,
    const float* __restrict__ W2, unsigned short* __restrict__ P2,
    const float* __restrict__ W3, unsigned short* __restrict__ P3,
    const float* __restrict__ W4, unsigned short* __restrict__ P4,
    int N)
{
    const int ln = threadIdx.x & 63;
    if (blockIdx.x < PREP_B) {
        const int gw = blockIdx.x * 4 + (threadIdx.x >> 6);
        if (gw >= 2 * N) return;
        const int isY = (gw < N);
        const int r = isY ? gw : gw - N;
        const int D = isY ? 120 : 100;
        const float* src = (isY ? YW : XW) + (size_t)r * D;
        unsigned short* dst = (isY ? ybf : xbf) + (size_t)r * 128;

        const float v0 = (ln < D) ? src[ln] : 0.f;
        const float v1 = (ln + 64 < D) ? src[ln + 64] : 0.f;
        float s = fmaf(v0, v0, v1 * v1);
        #pragma unroll
        for (int o = 1; o < 64; o <<= 1) s += __shfl_xor(s, o);
        if (ln == 0) (isY ? tny : tnx)[r] = s;

        dst[ln] = f2bf(v0);
        dst[ln + 64] = (ln == 63) ? f2bf(s) : f2bf(v1);
        return;
    }
    // ---- weight panel prep ----
    int b = (blockIdx.x - PREP_B) * 4 + (threadIdx.x >> 6);
    if (b >= 116) return;
    const float* W; unsigned short* P; int DK, DN, NT;
    if (b < 28)      {          W = W1; P = P1; DK = 100; DN = 100; NT = 7; }
    else if (b < 60) { b -= 28; W = W2; P = P2; DK = 100; DN = 120; NT = 8; }
    else if (b < 88) { b -= 60; W = W3; P = P3; DK = 120; DN = 100; NT = 7; }
    else             { b -= 88; W = W4; P = P4; DK = 100; DN = 100; NT = 7; }
    const int kt = b / NT, nt = b - kt * NT;
    const int n  = nt * 16 + (ln & 15);
    const int k0 = kt * 32 + (ln >> 4) * 8;
    unsigned short* dst = P + ((size_t)(kt * NT + nt) * 64 + ln) * 8;
    #pragma unroll
    for (int j = 0; j < 8; j++) {
        const int k = k0 + j;
        const float f = (k < DK && n < DN) ? W[k * DN + n] : 0.f;
        dst[j] = f2bf(f);
    }
}

// ---------------------------------------------------------------------------
// MFMA stage helpers (layouts HW-verified: absmax 0.0 R2-R7).
// ---------------------------------------------------------------------------
template<int NT>
__device__ inline void run_stage(const bf16x8 af[4], const unsigned short* __restrict__ WP,
                                 int ln, f32x4 acc[NT])
{
    #pragma unroll
    for (int nt = 0; nt < NT; nt++) acc[nt] = (f32x4){0.f, 0.f, 0.f, 0.f};
    #pragma unroll
    for (int kt = 0; kt < 4; kt++) {
        #pragma unroll
        for (int nt = 0; nt < NT; nt++) {
            const bf16x8 wf = *reinterpret_cast<const bf16x8*>(WP + ((size_t)(kt * NT + nt) * 64 + ln) * 8);
            acc[nt] = __builtin_amdgcn_mfma_f32_16x16x32_bf16(af[kt], wf, acc[nt], 0, 0, 0);
        }
    }
}

template<int NT, int DN, bool RELU>
__device__ inline void pack_h(const f32x4 acc[NT], const float* __restrict__ B,
                              unsigned short* __restrict__ Hs, int col, int quad)
{
    #pragma unroll
    for (int nt = 0; nt < NT; nt++) {
        const int n = nt * 16 + col;
        const float b = (n < DN) ? B[n] : 0.f;
        #pragma unroll
        for (int r = 0; r < 4; r++) {
            float v = acc[nt][r] + b;
            if (RELU) v = fmaxf(v, 0.f);
            Hs[(quad * 4 + r) * HS + n] = f2bf(v);
        }
    }
}

template<int NT, int DN>
__device__ inline void store_pack(const f32x4 acc[NT], const float* __restrict__ B,
                                  float* __restrict__ Y, unsigned short* __restrict__ Hs,
                                  int rowbase, int col, int quad, int N)
{
    #pragma unroll
    for (int nt = 0; nt < NT; nt++) {
        const int n = nt * 16 + col;
        const float b = (n < DN) ? B[n] : 0.f;
        #pragma unroll
        for (int r = 0; r < 4; r++) {
            const float v = acc[nt][r] + b;
            const int row = rowbase + quad * 4 + r;
            if (n < DN && row < N) Y[(size_t)row * DN + n] = v;
            Hs[(quad * 4 + r) * HS + n] = f2bf(v);
        }
    }
}

__device__ inline void load_haf(const unsigned short* __restrict__ Hs, int col, int quad,
                                bf16x8 af[4])
{
    const unsigned short* p = Hs + col * HS + quad * 8;
    #pragma unroll
    for (int kt = 0; kt < 4; kt++)
        af[kt] = *reinterpret_cast<const bf16x8*>(p + kt * 32);
}

template<int NT, int DN>
__device__ inline float norm_stage(const f32x4 acc[NT], const float* __restrict__ B,
                                   const float* __restrict__ REF,
                                   int rowbase, int col, int quad, int N)
{
    float ra[4] = {0.f, 0.f, 0.f, 0.f};
    #pragma unroll
    for (int nt = 0; nt < NT; nt++) {
        const int n = nt * 16 + col;
        if (n < DN) {
            const float b = B[n];
            #pragma unroll
            for (int r = 0; r < 4; r++) {
                const int row = rowbase + quad * 4 + r;
                if (row < N) {
                    const float d = acc[nt][r] + b - REF[(size_t)row * DN + n];
                    ra[r] = fmaf(d, d, ra[r]);
                }
            }
        }
    }
    #pragma unroll
    for (int o = 1; o < 16; o <<= 1) {
        #pragma unroll
        for (int r = 0; r < 4; r++) ra[r] += __shfl_xor(ra[r], o);
    }
    float s = 0.f;
    if (col == 0) {
        #pragma unroll
        for (int r = 0; r < 4; r++)
            if (rowbase + quad * 4 + r < N) s += sqrtf(ra[r]);
    }
    return s;
}

// ---------------------------------------------------------------------------
// Fused 4-stage MLP chain. 128-thread blocks (2 waves x 16 rows).
// ---------------------------------------------------------------------------
template<int DIN, int DMID, int NT2, int NTF>
__global__ __launch_bounds__(128) void mlp_fused(
    const unsigned short* __restrict__ Xbf,
    const float* __restrict__ XREF,
    const unsigned short* __restrict__ WP1, const float* __restrict__ B1,
    const unsigned short* __restrict__ WP2, const float* __restrict__ B2,
    const unsigned short* __restrict__ WP3, const float* __restrict__ B3,
    const unsigned short* __restrict__ WP4, const float* __restrict__ B4,
    float* __restrict__ Y,
    float* __restrict__ part, int N)
{
    __shared__ unsigned short H[2][16 * HS];
    __shared__ float bred[8];

    const int tid = threadIdx.x;
    const int wv = tid >> 6, ln = tid & 63;
    const int col = ln & 15, quad = ln >> 4;
    const int rowbase = blockIdx.x * 32 + wv * 16;

    {
        unsigned* Hz = reinterpret_cast<unsigned*>(H[wv]);
        for (int i = ln; i < 16 * HS / 2; i += 64) Hz[i] = 0u;
    }

    bf16x8 af[4];
    {
        const int r = min(rowbase + col, N - 1);
        const unsigned short* ap = Xbf + (size_t)r * 128 + quad * 8;
        #pragma unroll
        for (int kt = 0; kt < 4; kt++) af[kt] = *reinterpret_cast<const bf16x8*>(ap + kt * 32);
    }

    f32x4 accA[7];
    run_stage<7>(af, WP1, ln, accA);
    pack_h<7, HIDDEN, true>(accA, B1, H[wv], col, quad);
    load_haf(H[wv], col, quad, af);

    f32x4 accB[NT2];
    run_stage<NT2>(af, WP2, ln, accB);
    store_pack<NT2, DMID>(accB, B2, Y, H[wv], rowbase, col, quad, N);
    load_haf(H[wv], col, quad, af);

    run_stage<7>(af, WP3, ln, accA);
    pack_h<7, HIDDEN, true>(accA, B3, H[wv], col, quad);
    load_haf(H[wv], col, quad, af);

    f32x4 accC[NTF];
    run_stage<NTF>(af, WP4, ln, accC);
    const float s = norm_stage<NTF, DIN>(accC, B4, XREF, rowbase, col, quad, N);

    if (col == 0) bred[wv * 4 + quad] = s;
    __syncthreads();
    if (tid == 0) {
        float t = 0.f;
        #pragma unroll
        for (int i = 0; i < 8; i++) t += bred[i];
        part[blockIdx.x] = t;
    }
}

// ---------------------------------------------------------------------------
// sup: wave per pair; block partial -> ws.
// ---------------------------------------------------------------------------
__global__ __launch_bounds__(256) void sup_kernel(
    const float* __restrict__ xm, const float* __restrict__ ym,
    const float* __restrict__ xw, const float* __restrict__ yw,
    const int* __restrict__ im, int K, float* __restrict__ part)
{
    const int gw = (int)((blockIdx.x * 256 + threadIdx.x) >> 6);
    const int ln = threadIdx.x & 63;
    const int wv = threadIdx.x >> 6;
    float cnt = 0.f;
    if (gw < K) {
        const int xi = im[2 * gw], yi = im[2 * gw + 1];
        const float* a = xm + (size_t)xi * 120;
        const float* b = yw + (size_t)yi * 120;
        float s1 = 0.f;
        for (int d = ln; d < 120; d += 64) { const float df = a[d] - b[d]; s1 = fmaf(df, df, s1); }
        const float* c = ym + (size_t)yi * 100;
        const float* e = xw + (size_t)xi * 100;
        float s2 = 0.f;
        for (int d = ln; d < 100; d += 64) { const float df = c[d] - e[d]; s2 = fmaf(df, df, s2); }
        #pragma unroll
        for (int o = 32; o > 0; o >>= 1) { s1 += __shfl_down(s1, o); s2 += __shfl_down(s2, o); }
        if (ln == 0) cnt = sqrtf(s1) + sqrtf(s2);
    }
    __shared__ float wsum[4];
    if (ln == 0) wsum[wv] = cnt;
    __syncthreads();
    if (threadIdx.x == 0)
        part[blockIdx.x] = wsum[0] + wsum[1] + wsum[2] + wsum[3];
}

// ---------------------------------------------------------------------------
// Gather both query panels (scaled -2, col127=1) in one launch.
// ---------------------------------------------------------------------------
__global__ __launch_bounds__(256) void gather2(
    const float* __restrict__ xm, const float* __restrict__ ym,
    const int* __restrict__ gidx,
    unsigned short* __restrict__ axf, unsigned short* __restrict__ ayf, int K)
{
    const int t = blockIdx.x * 256 + threadIdx.x;
    if (t >= 2 * K * 128) return;
    const int dir = (t >= K * 128);
    const int tt = dir ? t - K * 128 : t;
    const int r = tt >> 7, c = tt & 127;
    const float* src = dir ? ym : xm;
    const int D = dir ? 100 : 120;
    float v = 0.f;
    if (c < D) v = -2.f * src[(size_t)gidx[r * 2 + dir] * D + c];
    else if (c == 127) v = 1.f;
    (dir ? ayf : axf)[tt] = f2bf(v);
}

// ---------------------------------------------------------------------------
// MFMA 1-NN, both directions via blockIdx.z. LDS: rm unioned onto bsm
// (17.4 KB). __launch_bounds__(256, 3): EMPIRICALLY the only safe value --
// R5 measured 72 VGPR no-spill with it; (256,4) gave 64 VGPR + 1.65 GB
// scratch FETCH (R7), (256,6) gave 40 VGPR + 2.7 GB (R6). Live set ~120.
// ---------------------------------------------------------------------------
__global__ __launch_bounds__(256, 3) void nn_mfma(
    const unsigned short* __restrict__ A0, const unsigned short* __restrict__ T0,
    float* __restrict__ pm0, int* __restrict__ pi0,
    const unsigned short* __restrict__ A1, const unsigned short* __restrict__ T1,
    float* __restrict__ pm1, int* __restrict__ pi1,
    int Ntgt, int K)
{
    constexpr int BS = 136;
    __shared__ unsigned short bsm[2][32 * BS];          // 17408 B
    float (*rm)[64][17] = reinterpret_cast<float(*)[64][17]>(&bsm[0][0]);  // alias, used after final sync

    const unsigned short* A = blockIdx.z ? A1 : A0;
    const unsigned short* T = blockIdx.z ? T1 : T0;
    float* pmin = blockIdx.z ? pm1 : pm0;
    int*   pidx = blockIdx.z ? pi1 : pi0;

    const int tid = threadIdx.x;
    const int wv = tid >> 6, ln = tid & 63;
    const int col = ln & 15, quad = ln >> 4;
    const int k0 = blockIdx.x * 256;
    const int jstart = blockIdx.y * CHUNK;
    const int jend = min(jstart + CHUNK, Ntgt);
    const int nt = (jend - jstart + 31) >> 5;

    bf16x8 afrag[4][4];
    #pragma unroll
    for (int t = 0; t < 4; t++) {
        const int ar = min(k0 + wv * 64 + t * 16 + col, K - 1);
        const unsigned short* ab = A + (size_t)ar * 128 + quad * 8;
        #pragma unroll
        for (int s = 0; s < 4; s++)
            afrag[t][s] = *reinterpret_cast<const bf16x8*>(ab + s * 32);
    }

    float m[4][4];
    #pragma unroll
    for (int t = 0; t < 4; t++)
        #pragma unroll
        for (int r = 0; r < 4; r++) m[t][r] = __builtin_inff();

    const unsigned bigw = ((unsigned)f2bf(1e30f)) << 16;

    {
        #pragma unroll
        for (int half = 0; half < 2; half++) {
            const int c = tid + half * 256;
            const int r = c >> 4, off = c & 15;
            const int j = jstart + r;
            uint4 v;
            if (j < jend) v = reinterpret_cast<const uint4*>(T + (size_t)j * 128)[off];
            else { v.x = 0; v.y = 0; v.z = 0; v.w = (off == 15) ? bigw : 0u; }
            *reinterpret_cast<uint4*>(&bsm[0][r * BS + off * 8]) = v;
        }
    }
    __syncthreads();

    for (int ti = 0; ti < nt; ti++) {
        const int cur = ti & 1;
        const bool have = (ti + 1 < nt);
        uint4 v0, v1;
        if (have) {
            #pragma unroll
            for (int half = 0; half < 2; half++) {
                const int c = tid + half * 256;
                const int r = c >> 4, off = c & 15;
                const int j = jstart + (ti + 1) * 32 + r;
                uint4 v;
                if (j < jend) v = reinterpret_cast<const uint4*>(T + (size_t)j * 128)[off];
                else { v.x = 0; v.y = 0; v.z = 0; v.w = (off == 15) ? bigw : 0u; }
                if (half == 0) v0 = v; else v1 = v;
            }
        }

        const unsigned short* buf = bsm[cur];
        const unsigned lowbase = (unsigned)((jstart + ti * 32) >> 4);
        #pragma unroll
        for (int sub = 0; sub < 2; sub++) {
            bf16x8 bfr[4];
            const unsigned short* bb = buf + (sub * 16 + col) * BS + quad * 8;
            #pragma unroll
            for (int s = 0; s < 4; s++)
                bfr[s] = *reinterpret_cast<const bf16x8*>(bb + s * 32);
            const unsigned low = lowbase + sub;
            #pragma unroll
            for (int t = 0; t < 4; t++) {
                f32x4 acc = {0.f, 0.f, 0.f, 0.f};
                #pragma unroll
                for (int s = 0; s < 4; s++)
                    acc = __builtin_amdgcn_mfma_f32_16x16x32_bf16(afrag[t][s], bfr[s], acc, 0, 0, 0);
                #pragma unroll
                for (int r = 0; r < 4; r++) {
                    const unsigned u = (__float_as_uint(acc[r]) & 0xFFFFF800u) | low;
                    m[t][r] = fminf(m[t][r], __uint_as_float(u));
                }
            }
        }

        if (have) {
            {
                const int c = tid, r = c >> 4, off = c & 15;
                *reinterpret_cast<uint4*>(&bsm[cur ^ 1][r * BS + off * 8]) = v0;
            }
            {
                const int c = tid + 256, r = c >> 4, off = c & 15;
                *reinterpret_cast<uint4*>(&bsm[cur ^ 1][r * BS + off * 8]) = v1;
            }
        }
        __syncthreads();
    }

    // ---- reduction (rm aliases bsm; all reads of bsm completed) ----
    #pragma unroll
    for (int t = 0; t < 4; t++)
        #pragma unroll
        for (int r = 0; r < 4; r++)
            rm[wv][t * 16 + quad * 4 + r][col] = m[t][r];
    __syncthreads();

    const int k = k0 + tid;
    if (k < K) {
        const int w = tid >> 6, rr = tid & 63;
        float best = rm[w][rr][0];
        int bc = 0;
        #pragma unroll
        for (int c = 1; c < 16; c++) {
            const float v = rm[w][rr][c];
            if (v < best) { best = v; bc = c; }
        }
        const int j = (int)(((__float_as_uint(best) & 0x7FFu) << 4) | (unsigned)bc);
        pmin[(size_t)k * NC + blockIdx.y] = best;
        pidx[(size_t)k * NC + blockIdx.y] = j;
    }
}

// ---------------------------------------------------------------------------
// finish_all: mismatch indicators + sup partials + mlp partials. 64 atomics.
// ---------------------------------------------------------------------------
__global__ __launch_bounds__(256) void finish_all(
    const int* __restrict__ im,
    const float* __restrict__ pm0, const int* __restrict__ pi0,
    const float* __restrict__ pm1, const int* __restrict__ pi1,
    const float* __restrict__ part_sup, const float* __restrict__ part_mlp,
    int K, float* __restrict__ out, float inv_k, float inv_n)
{
    const int gid = blockIdx.x * 256 + threadIdx.x;
    const int stride = gridDim.x * 256;
    float local = 0.f;

    for (int p = gid; p < 2 * K; p += stride) {
        const int dir = (p >= K);
        const int kk = dir ? p - K : p;
        const float* pm = dir ? pm1 : pm0;
        const int*   pi = dir ? pi1 : pi0;
        float best = __builtin_inff();
        int bi = 0x7fffffff;
        #pragma unroll
        for (int c = 0; c < NC; c++) {
            const float v = pm[(size_t)kk * NC + c];
            const int  ii = pi[(size_t)kk * NC + c];
            if (v < best || (v == best && ii < bi)) { best = v; bi = ii; }
        }
        if (bi != im[2 * kk + dir]) local += inv_k;
    }
    for (int i = gid; i < NB_SUP; i += stride) local += part_sup[i] * inv_k;
    for (int i = gid; i < NB_MLP; i += stride) local += part_mlp[i] * inv_n;

    #pragma unroll
    for (int o = 32; o > 0; o >>= 1) local += __shfl_down(local, o);
    __shared__ float wsum[4];
    if ((threadIdx.x & 63) == 0) wsum[threadIdx.x >> 6] = local;
    __syncthreads();
    if (threadIdx.x == 0) {
        const float t = wsum[0] + wsum[1] + wsum[2] + wsum[3];
        if (t != 0.f) atomicAdd(out, t);
    }
}

// ---------------------------------------------------------------------------
extern "C" void kernel_launch(void* const* d_in, const int* in_sizes, int n_in,
                              void* d_out, int out_size, void* d_ws, size_t ws_size,
                              hipStream_t stream)
{
    const float* xw    = (const float*)d_in[0];
    const float* yw    = (const float*)d_in[1];
    const float* fx_w1 = (const float*)d_in[2];
    const float* fx_b1 = (const float*)d_in[3];
    const float* fx_w2 = (const float*)d_in[4];
    const float* fx_b2 = (const float*)d_in[5];
    const float* gy_w1 = (const float*)d_in[6];
    const float* gy_b1 = (const float*)d_in[7];
    const float* gy_w2 = (const float*)d_in[8];
    const float* gy_b2 = (const float*)d_in[9];
    const int*   imap  = (const int*)d_in[10];
    float* out = (float*)d_out;
    float* ws  = (float*)d_ws;

    constexpr int N = NPTS, K = KPAIR;

    float* xm      = ws;                           // N*120
    float* ym      = xm + (size_t)N * 120;         // N*100
    float* tn_y    = ym + (size_t)N * 100;         // N
    float* tn_x    = tn_y + N;                     // N
    float* pmin_fx = tn_x + N;                     // K*NC
    int*   pidx_fx = (int*)(pmin_fx + (size_t)K * NC);
    float* pmin_gy = (float*)(pidx_fx + (size_t)K * NC);
    int*   pidx_gy = (int*)(pmin_gy + (size_t)K * NC);
    unsigned short* ybf = (unsigned short*)(pidx_gy + (size_t)K * NC); // N*128
    unsigned short* xbf = ybf + (size_t)N * 128;
    unsigned short* axf = xbf + (size_t)N * 128;   // K*128
    unsigned short* ayf = axf + (size_t)K * 128;
    unsigned short* wp_fx1 = ayf + (size_t)K * 128;  // 28*512
    unsigned short* wp_fx2 = wp_fx1 + 28 * 512;      // 32*512
    unsigned short* wp_gy1 = wp_fx2 + 32 * 512;      // 28*512
    unsigned short* wp_gy2 = wp_gy1 + 28 * 512;      // 28*512
    float* part_sup = (float*)(wp_gy2 + 28 * 512);   // NB_SUP
    float* part_mlp = part_sup + NB_SUP;             // NB_MLP

    hipMemsetAsync(d_out, 0, sizeof(float), stream);

    prep_kernel<<<PREP_B + 29, 256, 0, stream>>>(
        yw, tn_y, ybf, xw, tn_x, xbf,
        fx_w1, wp_fx1, fx_w2, wp_fx2, gy_w1, wp_gy1, gy_w2, wp_gy2, N);

    mlp_fused<100, 120, 8, 7><<<GM, 128, 0, stream>>>(
        xbf, xw, wp_fx1, fx_b1, wp_fx2, fx_b2, wp_gy1, gy_b1, wp_gy2, gy_b2,
        xm, part_mlp, N);
    mlp_fused<120, 100, 7, 8><<<GM, 128, 0, stream>>>(
        ybf, yw, wp_gy1, gy_b1, wp_gy2, gy_b2, wp_fx1, fx_b1, wp_fx2, fx_b2,
        ym, part_mlp + GM, N);

    sup_kernel<<<NB_SUP, 256, 0, stream>>>(xm, ym, xw, yw, imap, K, part_sup);

    gather2<<<(2 * K * 128) / 256, 256, 0, stream>>>(xm, ym, imap, axf, ayf, K);

    dim3 g1((K + 255) / 256, NC, 2);
    nn_mfma<<<g1, 256, 0, stream>>>(axf, ybf, pmin_fx, pidx_fx,
                                    ayf, xbf, pmin_gy, pidx_gy, N, K);

    finish_all<<<64, 256, 0, stream>>>(
        imap, pmin_fx, pidx_fx, pmin_gy, pidx_gy, part_sup, part_mlp,
        K, out, 1.f / K, 1.f / N);
}